// Round 3
// baseline (705.747 us; speedup 1.0000x reference)
//
#include <hip/hip_runtime.h>
#include <cmath>

typedef __bf16 bf16;
typedef __bf16 bf16x8 __attribute__((ext_vector_type(8)));
typedef float floatx4 __attribute__((ext_vector_type(4)));

#define E_ 8
#define M_ 2048
#define D_ 1024
#define F_ 4096

#define PUNROLL _Pragma("unroll")

__device__ __forceinline__ void async16(const void* g, void* l) {
    __builtin_amdgcn_global_load_lds((const __attribute__((address_space(1))) unsigned int*)g,
                                     (__attribute__((address_space(3))) unsigned int*)l, 16, 0, 0);
}

// tanh-approx GELU: x * sigmoid(1.59577x + 0.0713548x^3). Max dev from exact ~3e-3.
__device__ __forceinline__ float gelu_fast(float u) {
    float s = u * (-1.5957691216f - 0.0713548162726f * u * u);
    return u * __builtin_amdgcn_rcpf(1.0f + __expf(s));
}

// ---------------- fp32 -> bf16 elementwise, 16B stores (x only) ----------------
__global__ __launch_bounds__(256) void cvt_bf16_kernel(const float4* __restrict__ in,
                                                       bf16x8* __restrict__ out, int n8) {
    int i = blockIdx.x * 256 + threadIdx.x;
    int stride = gridDim.x * 256;
    for (; i < n8; i += stride) {
        float4 a = in[2 * i], b = in[2 * i + 1];
        bf16x8 r = {(bf16)a.x, (bf16)a.y, (bf16)a.z, (bf16)a.w,
                    (bf16)b.x, (bf16)b.y, (bf16)b.z, (bf16)b.w};
        out[i] = r;
    }
}

// ======================= 256x256 8-phase bf16 GEMM, B read DIRECTLY as fp32 [K,N] =============
// A (bf16 [M,K]): global_load_lds staging, source-preswizzled, unchanged from proven round-2.
// B (fp32 [K,N]): reg-staged with in-register transpose: wave w lane l loads 8 rows
//   (k = w*8..+7) of the same 16B col window (col = col0 + l*4) -> thread holds 8k x 4n fp32 ->
//   cvt -> 4x ds_write_b128, each a K-contiguous 8-elem bf16 run. LDS layout stays K-major.
// B slot swizzle: chunk c (16B, c=k>>3) of row r stored at byte slot (c ^ f(r))<<4 with
//   f(r) = (r ^ (r>>2)) & 7.  Reads (rows stride 1 per lane) AND writes (rows stride 4 per
//   lane) both cover 8 distinct slots per 8-lane group -> conflict-free both sides.
// Schedule per K-tile: ph0 issues B(t+1) loads + stages A-hi(t+1); ph1 stages A-lo(t+2);
//   ph3: vmcnt(2) [B(t+1)+A-hi(t+1) drained; A-lo(t+2) may fly], cvt+ds_write B(t+1)->pn,
//   lgkmcnt(0) BEFORE the barrier (cross-wave visibility), MFMA acc10.
// Hazards: B(t+1) overwrites B(t-1) (last read t-1.ph1, many barriers prior). A staging
//   hazards unchanged from round-2 (verified). nt must be even (16 and 64 here) so the
//   persistent-tile chaining restarts at buf0.
template <bool GELU>
__global__ __launch_bounds__(512, 2) void gemm256(const bf16* __restrict__ A0,
                                                  const float* __restrict__ Bf0,
                                                  const float* __restrict__ bias0,
                                                  void* __restrict__ Out,
                                                  int M, int N, int K, int tpb) {
    extern __shared__ __align__(16) char sm[];
    const int nt = K >> 6;   // K-tiles of 64
    const int NTm = M >> 8;
    const int NTn = N >> 8;
    const int nwg = gridDim.x;
    const int bid = blockIdx.x;
    // T1: bijective XCD swizzle (nwg % 8 == 0), tile-id = swz*tpb + j, tm fastest.
    const int swz = (bid & 7) * (nwg >> 3) + (bid >> 3);

    const int tid = threadIdx.x;
    const int l = tid & 63;
    const int w = tid >> 6;
    const int wm = w >> 2;   // 0..1
    const int wn = w & 3;    // 0..3

    // ---- A staging (global_load_lds, per-lane pre-swizzled source) ----
    const size_t Kb = (size_t)K * 2;       // A row stride in bytes
    const size_t half128 = 128 * Kb;       // +128 rows
    const size_t j64 = 64 * Kb;            // +64 rows
    const int srow = (w << 3) + (l >> 3);  // 0..63
    const int kb = ((l & 7) ^ ((l >> 3) & 7)) << 4;
    const int ldsW = w << 10;

    auto stage = [&](int hb, const char* src, int ko) {
        async16(src + ko, sm + hb + ldsW);
        async16(src + j64 + ko, sm + hb + 8192 + ldsW);
    };

    // ---- A fragment addressing (XOR-swizzled, unchanged) ----
    const int lq4 = l >> 4;  // 0..3
    const int kpat0 = ((lq4 ^ (l & 7)) << 4);
    const int kpat1 = (((4 | lq4) ^ (l & 7)) << 4);
    const int aRowOff = (((wm << 6) + (l & 15)) << 7);

    // ---- B fragment addressing: row = wn*32 + ni*16 + (l&15); slot = ((kk<<2)|lq4) ^ f(row)
    //      f(row) = (row&7) ^ ((row>>2)&7) = (l&7) ^ (ni<<2) ^ ((l&15)>>2)
    const int fB0 = (l & 7) ^ ((l & 15) >> 2);
    const int gB = lq4 ^ fB0;                  // slot(ni,kk) = gB ^ ((kk^ni)<<2)
    const int bRowByte = (((wn << 5) + (l & 15)) << 7);  // row*128 within half

    // ---- B write offsets: thread (w,l) owns rows r = l*4+j, chunk c = w ----
    int wOffB[4];
    PUNROLL
    for (int j = 0; j < 4; ++j) {
        const int r = l * 4 + j;  // 0..255
        const int slot = w ^ ((((l & 1) << 2) | j) ^ (l & 7));
        wOffB[j] = 32768 + ((r >> 7) << 14) + ((r & 127) << 7) + (slot << 4);
    }

    // ---- decode tile 0; issue its A prologue + B(0) loads ----
    int tile = swz * tpb;
    int tm = tile % NTm, rem = tile / NTm;
    int tn = rem % NTn, e = rem / NTn;
    int row0 = tm << 8, col0 = tn << 8;
    const char* aS = (const char*)A0 + ((size_t)e * M + row0 + srow) * Kb + kb;
    const float* bG = Bf0 + (size_t)e * K * N + (size_t)(w << 3) * N + col0 + (l << 2);

    float4 bpro[8];
    stage(0, aS, 0);                // A-lo(0) -> buf0
    stage(16384, aS + half128, 0);  // A-hi(0) -> buf0
    stage(65536, aS, 128);          // A-lo(1) -> buf1
    PUNROLL
    for (int r = 0; r < 8; ++r) bpro[r] = *(const float4*)(bG + (size_t)r * N);

    for (int j = 0; j < tpb; ++j) {
        // ---- head: drain prologue loads, write B(0) -> buf0, publish ----
        asm volatile("s_waitcnt vmcnt(0)" ::: "memory");
#define BWRITE0(JC, FLD)                                                                    \
    {                                                                                       \
        bf16x8 v = {(bf16)bpro[0].FLD, (bf16)bpro[1].FLD, (bf16)bpro[2].FLD,                \
                    (bf16)bpro[3].FLD, (bf16)bpro[4].FLD, (bf16)bpro[5].FLD,                \
                    (bf16)bpro[6].FLD, (bf16)bpro[7].FLD};                                  \
        *(bf16x8*)(sm + wOffB[JC]) = v;                                                     \
    }
        BWRITE0(0, x) BWRITE0(1, y) BWRITE0(2, z) BWRITE0(3, w)
        asm volatile("s_waitcnt lgkmcnt(0)" ::: "memory");
        __builtin_amdgcn_s_barrier();

        bf16x8 aa[4][2];
        bf16x8 bb0[2][2], bb1[2][2];
        floatx4 acc00[4][2] = {}, acc01[4][2] = {}, acc10[4][2] = {}, acc11[4][2] = {};

#define READ_A(QM)                                                                          \
    PUNROLL                                                                                 \
    for (int mi = 0; mi < 4; ++mi) {                                                        \
        aa[mi][0] = *(const bf16x8*)(sm + p + (QM)*16384 + aRowOff + mi * 2048 + kpat0);    \
        aa[mi][1] = *(const bf16x8*)(sm + p + (QM)*16384 + aRowOff + mi * 2048 + 64 + kpat1 - kpat0 - 64 + kpat1); \
    }
        // NOTE: the line above would be wrong; use the explicit form below instead.
#undef READ_A
#define READ_A(QM)                                                                          \
    PUNROLL                                                                                 \
    for (int mi = 0; mi < 4; ++mi) {                                                        \
        aa[mi][0] = *(const bf16x8*)(sm + p + (QM)*16384 + aRowOff + mi * 2048 + kpat0);    \
        aa[mi][1] = *(const bf16x8*)(sm + p + (QM)*16384 + aRowOff + mi * 2048 + kpat1);    \
    }
#define READ_B(BB, QN)                                                                      \
    PUNROLL                                                                                 \
    for (int ni = 0; ni < 2; ++ni) {                                                        \
        BB[ni][0] = *(const bf16x8*)(sm + p + 32768 + (QN)*16384 + bRowByte + ni * 2048 +   \
                                     ((gB ^ (ni << 2)) << 4));                              \
        BB[ni][1] = *(const bf16x8*)(sm + p + 32768 + (QN)*16384 + bRowByte + ni * 2048 +   \
                                     ((gB ^ 4 ^ (ni << 2)) << 4));                          \
    }
#define MQ(ACC, BB)                                                                         \
    PUNROLL                                                                                 \
    for (int mi = 0; mi < 4; ++mi) PUNROLL for (int ni = 0; ni < 2; ++ni) {                 \
        ACC[mi][ni] = __builtin_amdgcn_mfma_f32_16x16x32_bf16(aa[mi][0], BB[ni][0], ACC[mi][ni], 0, 0, 0); \
        ACC[mi][ni] = __builtin_amdgcn_mfma_f32_16x16x32_bf16(aa[mi][1], BB[ni][1], ACC[mi][ni], 0, 0, 0); \
    }
#define BWRITE(JC, FLD)                                                                     \
    {                                                                                       \
        bf16x8 v = {(bf16)breg[0].FLD, (bf16)breg[1].FLD, (bf16)breg[2].FLD,                \
                    (bf16)breg[3].FLD, (bf16)breg[4].FLD, (bf16)breg[5].FLD,                \
                    (bf16)breg[6].FLD, (bf16)breg[7].FLD};                                  \
        *(bf16x8*)(sm + pn + wOffB[JC]) = v;                                                \
    }

        for (int t = 0; t < nt; ++t) {
            const int p = (t & 1) << 16;
            const int pn = p ^ 65536;
            const int ko1 = (t + 1) << 7;
            const int ko2 = (t + 2) << 7;
            // ---- phase 0: (m-lo, n-lo); issue B(t+1) loads + stage A-hi(t+1) ----
            READ_A(0)
            READ_B(bb0, 0)
            float4 breg[8];
            if (t + 1 < nt) {
                stage(pn + 16384, aS + half128, ko1);  // A-hi(t+1) -> other buf
                const float* bp = bG + ((size_t)(t + 1) << 6) * N;
                PUNROLL
                for (int r = 0; r < 8; ++r) breg[r] = *(const float4*)(bp + (size_t)r * N);
            }
            __builtin_amdgcn_s_barrier();
            __builtin_amdgcn_s_setprio(1);
            MQ(acc00, bb0)
            __builtin_amdgcn_s_setprio(0);
            __builtin_amdgcn_s_barrier();
            // ---- phase 1: (m-lo, n-hi); stage A-lo(t+2) ----
            READ_B(bb1, 1)
            if (t + 2 < nt) stage(p + 0, aS, ko2);  // A-lo(t+2) -> this buf
            __builtin_amdgcn_s_barrier();
            __builtin_amdgcn_s_setprio(1);
            MQ(acc01, bb1)
            __builtin_amdgcn_s_setprio(0);
            __builtin_amdgcn_s_barrier();
            // ---- phase 2: (m-hi, n-hi) ----
            READ_A(1)
            __builtin_amdgcn_s_barrier();
            __builtin_amdgcn_s_setprio(1);
            MQ(acc11, bb1)
            __builtin_amdgcn_s_setprio(0);
            __builtin_amdgcn_s_barrier();
            // ---- phase 3: (m-hi, n-lo); land B(t+1) into pn ----
            if (t + 1 < nt) {
                if (t + 2 < nt)
                    asm volatile("s_waitcnt vmcnt(2)" ::: "memory");
                else
                    asm volatile("s_waitcnt vmcnt(0)" ::: "memory");
                BWRITE(0, x) BWRITE(1, y) BWRITE(2, z) BWRITE(3, w)
                asm volatile("s_waitcnt lgkmcnt(0)" ::: "memory");
            }
            __builtin_amdgcn_s_barrier();
            __builtin_amdgcn_s_setprio(1);
            MQ(acc10, bb0)
            __builtin_amdgcn_s_setprio(0);
            __builtin_amdgcn_s_barrier();
        }

        // ---- save epilogue params; issue next tile's prologue (hidden under epilogue) ----
        const int erow0 = row0, ecol0 = col0;
        const float* ebias = bias0 + (size_t)e * N;
        const size_t eout = (size_t)e * M * N;
        if (j + 1 < tpb) {
            tile = swz * tpb + j + 1;
            tm = tile % NTm; rem = tile / NTm;
            tn = rem % NTn; e = rem / NTn;
            row0 = tm << 8; col0 = tn << 8;
            aS = (const char*)A0 + ((size_t)e * M + row0 + srow) * Kb + kb;
            bG = Bf0 + (size_t)e * K * N + (size_t)(w << 3) * N + col0 + (l << 2);
            stage(0, aS, 0);
            stage(16384, aS + half128, 0);
            stage(65536, aS, 128);
            PUNROLL
            for (int r = 0; r < 8; ++r) bpro[r] = *(const float4*)(bG + (size_t)r * N);
        }

        // ---- epilogue: C/D layout col = lane&15, row = (lane>>4)*4 + reg ----
#define EPI(ACC, QM, QN)                                                                    \
    PUNROLL                                                                                 \
    for (int ni = 0; ni < 2; ++ni) {                                                        \
        const int col = ecol0 + (QN)*128 + (wn << 5) + ni * 16 + (l & 15);                  \
        const float bv = ebias[col];                                                        \
        PUNROLL                                                                             \
        for (int mi = 0; mi < 4; ++mi) {                                                    \
            const int row = erow0 + (QM)*128 + (wm << 6) + mi * 16 + ((l >> 4) << 2);       \
            PUNROLL                                                                         \
            for (int r = 0; r < 4; ++r) {                                                   \
                float v = ACC[mi][ni][r] + bv;                                              \
                if (GELU)                                                                   \
                    ((bf16*)Out)[eout + (size_t)(row + r) * N + col] = (bf16)gelu_fast(v);  \
                else                                                                        \
                    ((float*)Out)[eout + (size_t)(row + r) * N + col] = v;                  \
            }                                                                               \
        }                                                                                   \
    }
        EPI(acc00, 0, 0)
        EPI(acc01, 0, 1)
        EPI(acc11, 1, 1)
        EPI(acc10, 1, 0)
#undef READ_A
#undef READ_B
#undef MQ
#undef EPI
#undef BWRITE
#undef BWRITE0
    }
}

extern "C" void kernel_launch(void* const* d_in, const int* in_sizes, int n_in,
                              void* d_out, int out_size, void* d_ws, size_t ws_size,
                              hipStream_t stream) {
    const float* x = (const float*)d_in[0];
    const float* c_fc = (const float*)d_in[1];
    const float* c_proj = (const float*)d_in[2];
    const float* fc_bias = (const float*)d_in[3];
    const float* proj_bias = (const float*)d_in[4];
    float* out = (float*)d_out;

    const size_t EMD = (size_t)E_ * M_ * D_;  // 16.8M
    const size_t EMF = (size_t)E_ * M_ * F_;  // 67.1M
    bf16* xb = (bf16*)d_ws;
    bf16* h = xb + EMD;
    if (ws_size < (EMD + EMF) * 2) return;

    static bool attrDone = false;
    if (!attrDone) {
        (void)hipFuncSetAttribute((const void*)&gemm256<true>,
                                  hipFuncAttributeMaxDynamicSharedMemorySize, 131072);
        (void)hipFuncSetAttribute((const void*)&gemm256<false>,
                                  hipFuncAttributeMaxDynamicSharedMemorySize, 131072);
        attrDone = true;
    }

    // prep: only x -> bf16 (100 MB traffic). Weights are consumed fp32 in-GEMM.
    cvt_bf16_kernel<<<2048, 256, 0, stream>>>((const float4*)x, (bf16x8*)xb, E_ * M_ * D_ / 8);
    // GEMM1: [2048,1024]bf16 x c_fc fp32 [1024,4096] -> h bf16 + GELU.  1024 tiles, tpb=4.
    gemm256<true><<<256, 512, 131072, stream>>>(xb, c_fc, fc_bias, h, M_, F_, D_, 4);
    // GEMM2: [2048,4096]bf16 x c_proj fp32 [4096,1024] -> out fp32.  256 tiles, tpb=1.
    gemm256<false><<<256, 512, 131072, stream>>>(h, c_proj, proj_bias, out, M_, D_, F_, 1);
}